// Round 7
// baseline (948.431 us; speedup 1.0000x reference)
//
#include <hip/hip_runtime.h>
#include <stdint.h>

typedef __attribute__((ext_vector_type(8))) short short8;
typedef __attribute__((ext_vector_type(4))) float f32x4;
typedef __attribute__((ext_vector_type(4))) unsigned int u32x4;
typedef __attribute__((ext_vector_type(4))) unsigned short u16x4;

// B=8, S=2048, D=1024, H=64
// ws: Wb2 bf16 fragment-ordered [12 mtile][16 kchunk][2 ks][64 lane][8] @0 (384 KB)
//     Qw bf16 [16384][64] @393216 ; Kw @2490368 ; Vtw [512][2048] @4587520 ;
//     Op fp32 [4][16384][64] @6684672 (16 MB) ; lp fp32 [4][16384] @23461888

__device__ __forceinline__ unsigned short f2bf(float f){
  unsigned int u = __builtin_bit_cast(unsigned int, f);
  u = u + 0x7fffu + ((u >> 16) & 1u);
  return (unsigned short)(u >> 16);
}

// ---------------- kernel 0: W -> bf16 pack in MFMA-fragment order.
// A-frag (mt, kc, ks): lane qd*16+ln holds row h=mt*16+ln, cols kc*64+ks*32+qd*8..+7
__global__ __launch_bounds__(256) void wcvt_k(const float* __restrict__ Wk,
                                              const float* __restrict__ Wq,
                                              const float* __restrict__ Wv,
                                              unsigned short* __restrict__ Wb2){
  int t = blockIdx.x * 256 + threadIdx.x;
  int e = t * 8;
  int row = e >> 10, col = e & 1023;
  const float* src = (row < 64)  ? (Wq + row * 1024 + col)
                   : (row < 128) ? (Wk + (row - 64) * 1024 + col)
                   :               (Wv + (row - 128) * 1024 + col);
  f32x4 a = *(const f32x4*)src;
  f32x4 b = *(const f32x4*)(src + 4);
  u16x4 lo = { f2bf(a.x), f2bf(a.y), f2bf(a.z), f2bf(a.w) };
  u16x4 hi = { f2bf(b.x), f2bf(b.y), f2bf(b.z), f2bf(b.w) };
  const int mtile = row >> 4, lnn = row & 15;
  const int kchunk = col >> 6, ks = (col >> 5) & 1, qd = (col >> 3) & 3;
  const int lane = qd * 16 + lnn;
  const int off = ((((mtile * 16 + kchunk) * 2 + ks) * 64 + lane)) * 8;
  *(u16x4*)(Wb2 + off)     = lo;
  *(u16x4*)(Wb2 + off + 4) = hi;
}

// ---------------- kernel 1: QKV GEMM — s-tile 64, NO LDS, NO BARRIERS.
// grid 256 x 512 thr (8 waves). Wave: g=w&3 -> mtiles {3g..3g+2}; h=w>>2 -> ntiles {2h,2h+1}.
// W re-read per block drops 384->96 MB L2 (s-tile 16->64); X B-frags loaded straight
// into registers (fp32) and converted in-reg: the 4 g-waves share X slices via L1.
__global__ __launch_bounds__(512) void qkv_k(const float* __restrict__ X,
                                             const unsigned short* __restrict__ Wb2,
                                             unsigned short* __restrict__ Qw,
                                             unsigned short* __restrict__ Kw,
                                             unsigned short* __restrict__ Vtw){
  const int t = threadIdx.x, w = t >> 6, l = t & 63, qd = l >> 4, ln = l & 15;
  const int s0 = blockIdx.x * 64, b = s0 >> 11, sb = s0 & 2047;
  const int g = w & 3, h = w >> 2;
  const int mset = g * 3;
  // this lane's X row base for each of its 2 ntiles
  const float* xrow0 = X + (s0 + (2 * h + 0) * 16 + ln) * 1024 + qd * 8;
  const float* xrow1 = X + (s0 + (2 * h + 1) * 16 + ln) * 1024 + qd * 8;

  f32x4 acc[3][2];
#pragma unroll
  for (int i = 0; i < 3; ++i)
#pragma unroll
    for (int j = 0; j < 2; ++j) acc[i][j] = (f32x4){0.f, 0.f, 0.f, 0.f};

  short8 wreg[2][3][2];     // [buf][mt][ks]
  short8 bfr[2][2][2];      // [buf][nt][ks]
  f32x4 xf[2][2][2];        // [nt][ks][half] fp32 staging for next chunk

#pragma unroll
  for (int i = 0; i < 3; ++i)
#pragma unroll
    for (int ks = 0; ks < 2; ++ks)
      wreg[0][i][ks] = *(const short8*)(Wb2 + ((((mset + i) * 16 + 0) * 2 + ks) * 64 + l) * 8);
  // X chunk 0 -> regs -> bfr[0]
#pragma unroll
  for (int ks = 0; ks < 2; ++ks){
    xf[0][ks][0] = *(const f32x4*)(xrow0 + ks * 32);
    xf[0][ks][1] = *(const f32x4*)(xrow0 + ks * 32 + 4);
    xf[1][ks][0] = *(const f32x4*)(xrow1 + ks * 32);
    xf[1][ks][1] = *(const f32x4*)(xrow1 + ks * 32 + 4);
  }
#pragma unroll
  for (int nt = 0; nt < 2; ++nt)
#pragma unroll
    for (int ks = 0; ks < 2; ++ks){
      f32x4 a = xf[nt][ks][0], c = xf[nt][ks][1];
      bfr[0][nt][ks] = (short8){ (short)f2bf(a.x), (short)f2bf(a.y), (short)f2bf(a.z), (short)f2bf(a.w),
                                 (short)f2bf(c.x), (short)f2bf(c.y), (short)f2bf(c.z), (short)f2bf(c.w) };
    }
  // X chunk 1 -> regs
#pragma unroll
  for (int ks = 0; ks < 2; ++ks){
    xf[0][ks][0] = *(const f32x4*)(xrow0 + 64 + ks * 32);
    xf[0][ks][1] = *(const f32x4*)(xrow0 + 64 + ks * 32 + 4);
    xf[1][ks][0] = *(const f32x4*)(xrow1 + 64 + ks * 32);
    xf[1][ks][1] = *(const f32x4*)(xrow1 + 64 + ks * 32 + 4);
  }

  for (int kk = 0; kk < 16; ++kk){
    const int cur = kk & 1, nxt = cur ^ 1;
    if (kk < 15){
#pragma unroll
      for (int i = 0; i < 3; ++i)
#pragma unroll
        for (int ks = 0; ks < 2; ++ks)
          wreg[nxt][i][ks] = *(const short8*)(Wb2 + ((((mset + i) * 16 + kk + 1) * 2 + ks) * 64 + l) * 8);
    }
#pragma unroll
    for (int ks = 0; ks < 2; ++ks)
#pragma unroll
      for (int i = 0; i < 3; ++i)
#pragma unroll
        for (int j = 0; j < 2; ++j)
          acc[i][j] = __builtin_amdgcn_mfma_f32_16x16x32_bf16(wreg[cur][i][ks], bfr[cur][j][ks], acc[i][j], 0, 0, 0);
    if (kk < 15){
      // convert chunk kk+1 (in xf) -> bfr[nxt]
#pragma unroll
      for (int nt = 0; nt < 2; ++nt)
#pragma unroll
        for (int ks = 0; ks < 2; ++ks){
          f32x4 a = xf[nt][ks][0], c = xf[nt][ks][1];
          bfr[nxt][nt][ks] = (short8){ (short)f2bf(a.x), (short)f2bf(a.y), (short)f2bf(a.z), (short)f2bf(a.w),
                                       (short)f2bf(c.x), (short)f2bf(c.y), (short)f2bf(c.z), (short)f2bf(c.w) };
        }
      if (kk < 14){
        const int k0 = (kk + 2) * 64;
#pragma unroll
        for (int ks = 0; ks < 2; ++ks){
          xf[0][ks][0] = *(const f32x4*)(xrow0 + k0 + ks * 32);
          xf[0][ks][1] = *(const f32x4*)(xrow0 + k0 + ks * 32 + 4);
          xf[1][ks][0] = *(const f32x4*)(xrow1 + k0 + ks * 32);
          xf[1][ks][1] = *(const f32x4*)(xrow1 + k0 + ks * 32 + 4);
        }
      }
    }
  }
  // epilogue: D reg r -> hrow = (mset+i)*16 + qd*4 + r, col s = sb + (2h+j)*16 + ln
#pragma unroll
  for (int i = 0; i < 3; ++i){
    const int h0 = (mset + i) * 16 + qd * 4;
#pragma unroll
    for (int j = 0; j < 2; ++j){
      const int s = sb + (2 * h + j) * 16 + ln;
      f32x4 v = acc[i][j];
      u16x4 pk = { f2bf(v.x), f2bf(v.y), f2bf(v.z), f2bf(v.w) };
      if (h0 < 64){
        *(u16x4*)(Qw + (b * 2048 + s) * 64 + h0) = pk;
      } else if (h0 < 128){
        *(u16x4*)(Kw + (b * 2048 + s) * 64 + (h0 - 64)) = pk;
      } else {
        const int hh = h0 - 128;
        Vtw[(b * 64 + hh + 0) * 2048 + s] = pk.x;
        Vtw[(b * 64 + hh + 1) * 2048 + s] = pk.y;
        Vtw[(b * 64 + hh + 2) * 2048 + s] = pk.z;
        Vtw[(b * 64 + hh + 3) * 2048 + s] = pk.w;
      }
    }
  }
}

// ---------------- kernel 2: causal attention, kv-chunked (8 j-steps/chunk).
// grid 640 = 8 batch x 80 (qi,c) pairs, longest qi first. Private per-chunk
// partial buffers (no atomics/memsets). 4 waves x 16 q-rows, P wave-private,
// double-buffered K/V, 1 barrier/j-step, no-max softmax (bounded scores).
__global__ __launch_bounds__(256) void attn_k(const unsigned short* __restrict__ Qw,
                                              const unsigned short* __restrict__ Kw,
                                              const unsigned short* __restrict__ Vtw,
                                              float* __restrict__ Op,
                                              float* __restrict__ lp){
  __shared__ unsigned short Kl[2][64][72];
  __shared__ unsigned short Vl[2][64][72];
  __shared__ unsigned short Pl[4][16][72];
  const int t = threadIdx.x, w = t >> 6, l = t & 63, qd = l >> 4, ln = l & 15;
  const int b = blockIdx.x & 7;
  const int sp = blockIdx.x >> 3;
  int qi, c;
  if (sp < 32){ qi = 31 - (sp >> 2); c = sp & 3; }
  else if (sp < 56){ int u = sp - 32; int d = u / 3; qi = 23 - d; c = u - d * 3; }
  else if (sp < 72){ int u = sp - 56; qi = 15 - (u >> 1); c = u & 1; }
  else { qi = 7 - (sp - 72); c = 0; }
  const int jbeg = c * 8, jend = min(jbeg + 7, qi);
  const int q0 = b * 2048 + qi * 64, myq = w * 16, rowloc = qd * 4;
  const float c1 = 0.04508422f;                 // log2(e)/32

  short8 aQ[2];
#pragma unroll
  for (int ks = 0; ks < 2; ++ks)
    aQ[ks] = *(const short8*)(Qw + (q0 + myq + ln) * 64 + ks * 32 + qd * 8);

  f32x4 O[4];
#pragma unroll
  for (int i = 0; i < 4; ++i) O[i] = (f32x4){0.f,0.f,0.f,0.f};
  float lacc[4] = {0.f, 0.f, 0.f, 0.f};

  {
    const int kb = b * 2048 + jbeg * 64;
#pragma unroll
    for (int i = 0; i < 2; ++i){
      int cgl = t + i * 256, row = cgl >> 3, sub = cgl & 7;
      *(u32x4*)&Kl[0][row][sub * 8] = *(const u32x4*)(Kw + (kb + row) * 64 + sub * 8);
      *(u32x4*)&Vl[0][row][sub * 8] = *(const u32x4*)(Vtw + (b * 64 + row) * 2048 + jbeg * 64 + sub * 8);
    }
  }

  for (int j = jbeg; j <= jend; ++j){
    __syncthreads();
    const int cur = (j - jbeg) & 1, nxt = cur ^ 1;
    u32x4 kreg[2], vreg[2];
    if (j < jend){
      const int kb = b * 2048 + (j + 1) * 64;
#pragma unroll
      for (int i = 0; i < 2; ++i){
        int cgl = t + i * 256, row = cgl >> 3, sub = cgl & 7;
        kreg[i] = *(const u32x4*)(Kw + (kb + row) * 64 + sub * 8);
        vreg[i] = *(const u32x4*)(Vtw + (b * 64 + row) * 2048 + (j + 1) * 64 + sub * 8);
      }
    }
    f32x4 S[4];
#pragma unroll
    for (int nt = 0; nt < 4; ++nt) S[nt] = (f32x4){0.f,0.f,0.f,0.f};
#pragma unroll
    for (int ks = 0; ks < 2; ++ks)
#pragma unroll
      for (int nt = 0; nt < 4; ++nt){
        short8 bK = *(const short8*)&Kl[cur][nt * 16 + ln][ks * 32 + qd * 8];
        S[nt] = __builtin_amdgcn_mfma_f32_16x16x32_bf16(aQ[ks], bK, S[nt], 0, 0, 0);
      }
    const bool dtile = (j == qi);
#pragma unroll
    for (int nt = 0; nt < 4; ++nt){
      const int cl = nt * 16 + ln;
      f32x4 sv = S[nt];
#pragma unroll
      for (int r = 0; r < 4; ++r){
        float p = __builtin_amdgcn_exp2f(sv[r] * c1);
        if (dtile && cl > myq + rowloc + r) p = 0.f;
        lacc[r] += p;
        Pl[w][rowloc + r][cl] = f2bf(p);
      }
    }
#pragma unroll
    for (int ks = 0; ks < 2; ++ks){
      short8 aP = *(const short8*)&Pl[w][ln][ks * 32 + qd * 8];
#pragma unroll
      for (int ht = 0; ht < 4; ++ht){
        short8 bV = *(const short8*)&Vl[cur][ht * 16 + ln][ks * 32 + qd * 8];
        O[ht] = __builtin_amdgcn_mfma_f32_16x16x32_bf16(aP, bV, O[ht], 0, 0, 0);
      }
    }
    if (j < jend){
#pragma unroll
      for (int i = 0; i < 2; ++i){
        int cgl = t + i * 256, row = cgl >> 3, sub = cgl & 7;
        *(u32x4*)&Kl[nxt][row][sub * 8] = kreg[i];
        *(u32x4*)&Vl[nxt][row][sub * 8] = vreg[i];
      }
    }
  }

  float lred[4];
#pragma unroll
  for (int r = 0; r < 4; ++r){
    float v = lacc[r];
    v += __shfl_xor(v, 1);
    v += __shfl_xor(v, 2);
    v += __shfl_xor(v, 4);
    v += __shfl_xor(v, 8);
    lred[r] = v;
  }
  float* Opc = Op + c * 1048576;
  float* lpc = lp + c * 16384;
#pragma unroll
  for (int r = 0; r < 4; ++r){
    const int rowg = q0 + myq + rowloc + r;
#pragma unroll
    for (int ht = 0; ht < 4; ++ht)
      Opc[rowg * 64 + ht * 16 + ln] = O[ht][r];
    if (ln == 0) lpc[rowg] = lred[r];
  }
}

// ---------------- kernel 3: sum valid chunk partials + normalize
__global__ __launch_bounds__(256) void nrm_k(const float* __restrict__ Op,
                                             const float* __restrict__ lp,
                                             float* __restrict__ out){
  const int idx = (blockIdx.x * 256 + threadIdx.x) * 4;
  const int row = idx >> 6;
  const int qi = (row >> 6) & 31;
  const int nch = (qi >> 3) + 1;
  f32x4 s = (f32x4){0.f,0.f,0.f,0.f};
  float lsum = 0.f;
  for (int c = 0; c < nch; ++c){
    f32x4 v = *(const f32x4*)(Op + c * 1048576 + idx);
    s.x += v.x; s.y += v.y; s.z += v.z; s.w += v.w;
    lsum += lp[c * 16384 + row];
  }
  const float inv = 1.0f / lsum;
  s.x *= inv; s.y *= inv; s.z *= inv; s.w *= inv;
  *(f32x4*)(out + idx) = s;
}

extern "C" void kernel_launch(void* const* d_in, const int* in_sizes, int n_in,
                              void* d_out, int out_size, void* d_ws, size_t ws_size,
                              hipStream_t stream){
  const float* X  = (const float*)d_in[0];
  const float* Wk = (const float*)d_in[1];
  const float* Wq = (const float*)d_in[2];
  const float* Wv = (const float*)d_in[3];
  float* out = (float*)d_out;
  char* ws = (char*)d_ws;
  unsigned short* Wb2 = (unsigned short*)(ws);
  unsigned short* Qw  = (unsigned short*)(ws + 393216);
  unsigned short* Kw  = (unsigned short*)(ws + 2490368);
  unsigned short* Vtw = (unsigned short*)(ws + 4587520);
  float* Op = (float*)(ws + 6684672);
  float* lp = (float*)(ws + 23461888);

  hipLaunchKernelGGL(wcvt_k, dim3(96),  dim3(256), 0, stream, Wk, Wq, Wv, Wb2);
  hipLaunchKernelGGL(qkv_k,  dim3(256), dim3(512), 0, stream, X, Wb2, Qw, Kw, Vtw);
  hipLaunchKernelGGL(attn_k, dim3(640), dim3(256), 0, stream, Qw, Kw, Vtw, Op, lp);
  hipLaunchKernelGGL(nrm_k,  dim3(1024), dim3(256), 0, stream, Op, lp, out);
}

// Round 8
// 140.176 us; speedup vs baseline: 6.7660x; 6.7660x over previous
//
#include <hip/hip_runtime.h>
#include <stdint.h>

typedef __attribute__((ext_vector_type(8))) short short8;
typedef __attribute__((ext_vector_type(4))) float f32x4;
typedef __attribute__((ext_vector_type(4))) unsigned int u32x4;
typedef __attribute__((ext_vector_type(4))) unsigned short u16x4;

// B=8, S=2048, D=1024, H=64
// ws: Wb2 bf16 A-frag order [12 mt][16 kc][2 ks][64 lane][8] @0 (384 KB)
//     Qw bf16 [16384][64] @393216 ; Kw @2490368 ; Vtw [512][2048] @4587520 ;
//     Op fp32 [4][16384][64] @6684672 ; lp fp32 [4][16384] @23461888 ;
//     Xb bf16 B-frag order [1024 nt][16 kc][2 ks][64 lane][8] @23724032 (32 MB)

__device__ __forceinline__ unsigned short f2bf(float f){
  unsigned int u = __builtin_bit_cast(unsigned int, f);
  u = u + 0x7fffu + ((u >> 16) & 1u);
  return (unsigned short)(u >> 16);
}

// ---------------- kernel 0: W -> bf16 A-fragment pack
__global__ __launch_bounds__(256) void wcvt_k(const float* __restrict__ Wk,
                                              const float* __restrict__ Wq,
                                              const float* __restrict__ Wv,
                                              unsigned short* __restrict__ Wb2){
  int t = blockIdx.x * 256 + threadIdx.x;
  int e = t * 8;
  int row = e >> 10, col = e & 1023;
  const float* src = (row < 64)  ? (Wq + row * 1024 + col)
                   : (row < 128) ? (Wk + (row - 64) * 1024 + col)
                   :               (Wv + (row - 128) * 1024 + col);
  f32x4 a = *(const f32x4*)src;
  f32x4 b = *(const f32x4*)(src + 4);
  u16x4 lo = { f2bf(a.x), f2bf(a.y), f2bf(a.z), f2bf(a.w) };
  u16x4 hi = { f2bf(b.x), f2bf(b.y), f2bf(b.z), f2bf(b.w) };
  const int mtile = row >> 4, lnn = row & 15;
  const int kchunk = col >> 6, ks = (col >> 5) & 1, qd = (col >> 3) & 3;
  const int lane = qd * 16 + lnn;
  const int off = ((((mtile * 16 + kchunk) * 2 + ks) * 64 + lane)) * 8;
  *(u16x4*)(Wb2 + off)     = lo;
  *(u16x4*)(Wb2 + off + 4) = hi;
}

// ---------------- kernel 0b: X -> bf16 B-fragment pack (streaming, 96 MB)
// slot tid: lane=tid&63, ks=(tid>>6)&1, kc=(tid>>7)&15, nt=tid>>11.
// data = X[nt*16 + (lane&15)][kc*64 + ks*32 + (lane>>4)*8 .. +7]; write 16B coalesced.
__global__ __launch_bounds__(256) void xcvt_k(const float* __restrict__ X,
                                              unsigned short* __restrict__ Xb){
  const int tid = blockIdx.x * 256 + threadIdx.x;       // 2,097,152 slots
  const int lane = tid & 63, ks = (tid >> 6) & 1, kc = (tid >> 7) & 15, nt = tid >> 11;
  const int row = nt * 16 + (lane & 15);
  const int col = kc * 64 + ks * 32 + (lane >> 4) * 8;
  const float* xp = X + row * 1024 + col;
  f32x4 a = *(const f32x4*)xp;
  f32x4 b = *(const f32x4*)(xp + 4);
  u16x4 lo = { f2bf(a.x), f2bf(a.y), f2bf(a.z), f2bf(a.w) };
  u16x4 hi = { f2bf(b.x), f2bf(b.y), f2bf(b.z), f2bf(b.w) };
  *(u16x4*)(Xb + tid * 8)     = lo;
  *(u16x4*)(Xb + tid * 8 + 4) = hi;
}

// ---------------- kernel 1: pure-bf16 QKV GEMM. grid 256 x 512 thr (8 waves).
// Wave (g=w&3, h=w>>2): A mtiles {3g..3g+2}, B ntiles {2h,2h+1}. All operand
// loads are coalesced 1KB dwordx4 from fragment-packed Wb2/Xb. NO LDS, NO
// barriers, NO conversions. kk-loop FULLY UNROLLED so dbuf indices are static
// (R7's scratch-spill lesson).
__global__ __launch_bounds__(512) void qkv2_k(const unsigned short* __restrict__ Xb,
                                              const unsigned short* __restrict__ Wb2,
                                              unsigned short* __restrict__ Qw,
                                              unsigned short* __restrict__ Kw,
                                              unsigned short* __restrict__ Vtw){
  const int t = threadIdx.x, w = t >> 6, l = t & 63, qd = l >> 4, ln = l & 15;
  const int s0 = blockIdx.x * 64, b = s0 >> 11, sb = s0 & 2047;
  const int g = w & 3, h = w >> 2, mset = g * 3;
  const int nt0 = (s0 >> 4) + 2 * h;            // global ntile of this wave's first n-tile

  f32x4 acc[3][2];
#pragma unroll
  for (int i = 0; i < 3; ++i)
#pragma unroll
    for (int j = 0; j < 2; ++j) acc[i][j] = (f32x4){0.f, 0.f, 0.f, 0.f};

  short8 wreg[2][3][2];     // [buf][mt][ks]
  short8 breg[2][2][2];     // [buf][nt][ks]

#pragma unroll
  for (int i = 0; i < 3; ++i)
#pragma unroll
    for (int ks = 0; ks < 2; ++ks)
      wreg[0][i][ks] = *(const short8*)(Wb2 + ((((mset + i) * 16 + 0) * 2 + ks) * 64 + l) * 8);
#pragma unroll
  for (int j = 0; j < 2; ++j)
#pragma unroll
    for (int ks = 0; ks < 2; ++ks)
      breg[0][j][ks] = *(const short8*)(Xb + ((((nt0 + j) * 16 + 0) * 2 + ks) * 64 + l) * 8);

#pragma unroll
  for (int kk = 0; kk < 16; ++kk){
    const int cur = kk & 1, nxt = cur ^ 1;
    if (kk < 15){
#pragma unroll
      for (int i = 0; i < 3; ++i)
#pragma unroll
        for (int ks = 0; ks < 2; ++ks)
          wreg[nxt][i][ks] = *(const short8*)(Wb2 + ((((mset + i) * 16 + kk + 1) * 2 + ks) * 64 + l) * 8);
#pragma unroll
      for (int j = 0; j < 2; ++j)
#pragma unroll
        for (int ks = 0; ks < 2; ++ks)
          breg[nxt][j][ks] = *(const short8*)(Xb + ((((nt0 + j) * 16 + kk + 1) * 2 + ks) * 64 + l) * 8);
    }
#pragma unroll
    for (int ks = 0; ks < 2; ++ks)
#pragma unroll
      for (int i = 0; i < 3; ++i)
#pragma unroll
        for (int j = 0; j < 2; ++j)
          acc[i][j] = __builtin_amdgcn_mfma_f32_16x16x32_bf16(wreg[cur][i][ks], breg[cur][j][ks], acc[i][j], 0, 0, 0);
  }
  // epilogue: D reg r -> hrow = (mset+i)*16 + qd*4 + r, col s = sb + (2h+j)*16 + ln
#pragma unroll
  for (int i = 0; i < 3; ++i){
    const int h0 = (mset + i) * 16 + qd * 4;
#pragma unroll
    for (int j = 0; j < 2; ++j){
      const int s = sb + (2 * h + j) * 16 + ln;
      f32x4 v = acc[i][j];
      u16x4 pk = { f2bf(v.x), f2bf(v.y), f2bf(v.z), f2bf(v.w) };
      if (h0 < 64){
        *(u16x4*)(Qw + (b * 2048 + s) * 64 + h0) = pk;
      } else if (h0 < 128){
        *(u16x4*)(Kw + (b * 2048 + s) * 64 + (h0 - 64)) = pk;
      } else {
        const int hh = h0 - 128;
        Vtw[(b * 64 + hh + 0) * 2048 + s] = pk.x;
        Vtw[(b * 64 + hh + 1) * 2048 + s] = pk.y;
        Vtw[(b * 64 + hh + 2) * 2048 + s] = pk.z;
        Vtw[(b * 64 + hh + 3) * 2048 + s] = pk.w;
      }
    }
  }
}

// ---------------- kernel 2: causal attention, kv-chunked (8 j-steps/chunk).
// grid 640 = 8 batch x 80 (qi,c) pairs. Private per-chunk partial buffers.
// 4 waves x 16 q-rows, P wave-private, dbuf K/V, 1 barrier/j-step, no-max softmax.
__global__ __launch_bounds__(256) void attn_k(const unsigned short* __restrict__ Qw,
                                              const unsigned short* __restrict__ Kw,
                                              const unsigned short* __restrict__ Vtw,
                                              float* __restrict__ Op,
                                              float* __restrict__ lp){
  __shared__ unsigned short Kl[2][64][72];
  __shared__ unsigned short Vl[2][64][72];
  __shared__ unsigned short Pl[4][16][72];
  const int t = threadIdx.x, w = t >> 6, l = t & 63, qd = l >> 4, ln = l & 15;
  const int b = blockIdx.x & 7;
  const int sp = blockIdx.x >> 3;
  int qi, c;
  if (sp < 32){ qi = 31 - (sp >> 2); c = sp & 3; }
  else if (sp < 56){ int u = sp - 32; int d = u / 3; qi = 23 - d; c = u - d * 3; }
  else if (sp < 72){ int u = sp - 56; qi = 15 - (u >> 1); c = u & 1; }
  else { qi = 7 - (sp - 72); c = 0; }
  const int jbeg = c * 8, jend = min(jbeg + 7, qi);
  const int q0 = b * 2048 + qi * 64, myq = w * 16, rowloc = qd * 4;
  const float c1 = 0.04508422f;                 // log2(e)/32

  short8 aQ[2];
#pragma unroll
  for (int ks = 0; ks < 2; ++ks)
    aQ[ks] = *(const short8*)(Qw + (q0 + myq + ln) * 64 + ks * 32 + qd * 8);

  f32x4 O[4];
#pragma unroll
  for (int i = 0; i < 4; ++i) O[i] = (f32x4){0.f,0.f,0.f,0.f};
  float lacc[4] = {0.f, 0.f, 0.f, 0.f};

  {
    const int kb = b * 2048 + jbeg * 64;
#pragma unroll
    for (int i = 0; i < 2; ++i){
      int cgl = t + i * 256, row = cgl >> 3, sub = cgl & 7;
      *(u32x4*)&Kl[0][row][sub * 8] = *(const u32x4*)(Kw + (kb + row) * 64 + sub * 8);
      *(u32x4*)&Vl[0][row][sub * 8] = *(const u32x4*)(Vtw + (b * 64 + row) * 2048 + jbeg * 64 + sub * 8);
    }
  }

  for (int j = jbeg; j <= jend; ++j){
    __syncthreads();
    const int cur = (j - jbeg) & 1, nxt = cur ^ 1;
    u32x4 kreg[2], vreg[2];
    if (j < jend){
      const int kb = b * 2048 + (j + 1) * 64;
#pragma unroll
      for (int i = 0; i < 2; ++i){
        int cgl = t + i * 256, row = cgl >> 3, sub = cgl & 7;
        kreg[i] = *(const u32x4*)(Kw + (kb + row) * 64 + sub * 8);
        vreg[i] = *(const u32x4*)(Vtw + (b * 64 + row) * 2048 + (j + 1) * 64 + sub * 8);
      }
    }
    f32x4 S[4];
#pragma unroll
    for (int nt = 0; nt < 4; ++nt) S[nt] = (f32x4){0.f,0.f,0.f,0.f};
#pragma unroll
    for (int ks = 0; ks < 2; ++ks)
#pragma unroll
      for (int nt = 0; nt < 4; ++nt){
        short8 bK = *(const short8*)&Kl[cur][nt * 16 + ln][ks * 32 + qd * 8];
        S[nt] = __builtin_amdgcn_mfma_f32_16x16x32_bf16(aQ[ks], bK, S[nt], 0, 0, 0);
      }
    const bool dtile = (j == qi);
#pragma unroll
    for (int nt = 0; nt < 4; ++nt){
      const int cl = nt * 16 + ln;
      f32x4 sv = S[nt];
#pragma unroll
      for (int r = 0; r < 4; ++r){
        float p = __builtin_amdgcn_exp2f(sv[r] * c1);
        if (dtile && cl > myq + rowloc + r) p = 0.f;
        lacc[r] += p;
        Pl[w][rowloc + r][cl] = f2bf(p);
      }
    }
#pragma unroll
    for (int ks = 0; ks < 2; ++ks){
      short8 aP = *(const short8*)&Pl[w][ln][ks * 32 + qd * 8];
#pragma unroll
      for (int ht = 0; ht < 4; ++ht){
        short8 bV = *(const short8*)&Vl[cur][ht * 16 + ln][ks * 32 + qd * 8];
        O[ht] = __builtin_amdgcn_mfma_f32_16x16x32_bf16(aP, bV, O[ht], 0, 0, 0);
      }
    }
    if (j < jend){
#pragma unroll
      for (int i = 0; i < 2; ++i){
        int cgl = t + i * 256, row = cgl >> 3, sub = cgl & 7;
        *(u32x4*)&Kl[nxt][row][sub * 8] = kreg[i];
        *(u32x4*)&Vl[nxt][row][sub * 8] = vreg[i];
      }
    }
  }

  float lred[4];
#pragma unroll
  for (int r = 0; r < 4; ++r){
    float v = lacc[r];
    v += __shfl_xor(v, 1);
    v += __shfl_xor(v, 2);
    v += __shfl_xor(v, 4);
    v += __shfl_xor(v, 8);
    lred[r] = v;
  }
  float* Opc = Op + c * 1048576;
  float* lpc = lp + c * 16384;
#pragma unroll
  for (int r = 0; r < 4; ++r){
    const int rowg = q0 + myq + rowloc + r;
#pragma unroll
    for (int ht = 0; ht < 4; ++ht)
      Opc[rowg * 64 + ht * 16 + ln] = O[ht][r];
    if (ln == 0) lpc[rowg] = lred[r];
  }
}

// ---------------- kernel 3: sum valid chunk partials + normalize
__global__ __launch_bounds__(256) void nrm_k(const float* __restrict__ Op,
                                             const float* __restrict__ lp,
                                             float* __restrict__ out){
  const int idx = (blockIdx.x * 256 + threadIdx.x) * 4;
  const int row = idx >> 6;
  const int qi = (row >> 6) & 31;
  const int nch = (qi >> 3) + 1;
  f32x4 s = (f32x4){0.f,0.f,0.f,0.f};
  float lsum = 0.f;
  for (int c = 0; c < nch; ++c){
    f32x4 v = *(const f32x4*)(Op + c * 1048576 + idx);
    s.x += v.x; s.y += v.y; s.z += v.z; s.w += v.w;
    lsum += lp[c * 16384 + row];
  }
  const float inv = 1.0f / lsum;
  s.x *= inv; s.y *= inv; s.z *= inv; s.w *= inv;
  *(f32x4*)(out + idx) = s;
}

extern "C" void kernel_launch(void* const* d_in, const int* in_sizes, int n_in,
                              void* d_out, int out_size, void* d_ws, size_t ws_size,
                              hipStream_t stream){
  const float* X  = (const float*)d_in[0];
  const float* Wk = (const float*)d_in[1];
  const float* Wq = (const float*)d_in[2];
  const float* Wv = (const float*)d_in[3];
  float* out = (float*)d_out;
  char* ws = (char*)d_ws;
  unsigned short* Wb2 = (unsigned short*)(ws);
  unsigned short* Qw  = (unsigned short*)(ws + 393216);
  unsigned short* Kw  = (unsigned short*)(ws + 2490368);
  unsigned short* Vtw = (unsigned short*)(ws + 4587520);
  float* Op = (float*)(ws + 6684672);
  float* lp = (float*)(ws + 23461888);
  unsigned short* Xb  = (unsigned short*)(ws + 23724032);

  hipLaunchKernelGGL(wcvt_k,  dim3(96),   dim3(256), 0, stream, Wk, Wq, Wv, Wb2);
  hipLaunchKernelGGL(xcvt_k,  dim3(8192), dim3(256), 0, stream, X, Xb);
  hipLaunchKernelGGL(qkv2_k,  dim3(256),  dim3(512), 0, stream, Xb, Wb2, Qw, Kw, Vtw);
  hipLaunchKernelGGL(attn_k,  dim3(640),  dim3(256), 0, stream, Qw, Kw, Vtw, Op, lp);
  hipLaunchKernelGGL(nrm_k,   dim3(1024), dim3(256), 0, stream, Op, lp, out);
}